// Round 1
// baseline (354.179 us; speedup 1.0000x reference)
//
#include <hip/hip_runtime.h>
#include <cfloat>
#include <math.h>

#define N_TOK 32768
#define DIM   256
#define MCODE 1024

constexpr float DECAY_ = 0.999f;
constexpr float OMD_   = (float)(1.0 - 0.999);   // match jax double->f32 promotion
constexpr float EPS_   = 1e-5f;
constexpr float MEPS_  = (float)(1024 * 1e-5);   // M * EPS in double, then f32

// ---- workspace layout (float offsets) ----
constexpr int WS_ET   = 0;        // eT[256][1024]      (262144)
constexpr int WS_ESQ  = 262144;   // esq[1024]
constexpr int WS_CNT  = 263168;   // counts[1024]       (zeroed)
constexpr int WS_DW   = 264192;   // dw[1024][256]      (zeroed)
constexpr int WS_LP   = 526336;   // loss partials[4096]
constexpr int WS_CVAL = 559104;   // cand vals [4][32768]
constexpr int WS_CIDX = 690176;   // cand idx  [4][32768] (as int)
// total ~3.3 MB

// ---- output layout (float offsets) ----
constexpr int OUT_Q        = 0;
constexpr int OUT_COMMIT   = 8388608;
constexpr int OUT_CODEBOOK = 8388609;
constexpr int OUT_PERP     = 8388610;
constexpr int OUT_NE       = 8388611;
constexpr int OUT_NC       = 8650755;
constexpr int OUT_NW       = 8651779;

__global__ __launch_bounds__(256) void vq_zero(float* __restrict__ p, int n) {
    int i = blockIdx.x * 256 + threadIdx.x;
    if (i < n) p[i] = 0.f;
}

// one block (64 threads) per code: esq[c] = sum_d e[c][d]^2
__global__ __launch_bounds__(64) void vq_esq(const float* __restrict__ emb,
                                             float* __restrict__ esq) {
    int c = blockIdx.x, l = threadIdx.x;
    float4 v = *(const float4*)&emb[c * DIM + l * 4];
    float s = v.x * v.x + v.y * v.y + v.z * v.z + v.w * v.w;
#pragma unroll
    for (int off = 32; off; off >>= 1) s += __shfl_xor(s, off, 64);
    if (l == 0) esq[c] = s;
}

// tiled transpose: emb[M][D] -> eT[D][M]; 64x64 tiles via LDS (stride 65, conflict-free)
__global__ __launch_bounds__(256) void vq_transpose(const float* __restrict__ emb,
                                                    float* __restrict__ eT) {
    __shared__ float t[64 * 65];
    const int tid = threadIdx.x;
    const int c0 = (blockIdx.x >> 2) * 64, d0 = (blockIdx.x & 3) * 64;
#pragma unroll
    for (int it = 0; it < 4; ++it) {
        int idx = it * 256 + tid;          // 1024 float4 loads
        int ci = idx >> 4, dq = idx & 15;
        float4 v = *(const float4*)&emb[(c0 + ci) * DIM + d0 + dq * 4];
        t[ci * 65 + dq * 4 + 0] = v.x;
        t[ci * 65 + dq * 4 + 1] = v.y;
        t[ci * 65 + dq * 4 + 2] = v.z;
        t[ci * 65 + dq * 4 + 3] = v.w;
    }
    __syncthreads();
#pragma unroll
    for (int it = 0; it < 4; ++it) {
        int idx = it * 256 + tid;
        int di = idx >> 4, cq = idx & 15;
        float4 v;
        v.x = t[(cq * 4 + 0) * 65 + di];
        v.y = t[(cq * 4 + 1) * 65 + di];
        v.z = t[(cq * 4 + 2) * 65 + di];
        v.w = t[(cq * 4 + 3) * 65 + di];
        *(float4*)&eT[(d0 + di) * MCODE + c0 + cq * 4] = v;
    }
}

// main: grid 1024 = 256 row-blocks x 4 col-splits.
// block: 128 rows x 256 cols (2 tiles of 128), thread micro-tile 8x8.
// dist = esq[c] - 2 * dot(x,e); per-row (min,argmin) candidate per col-split.
__global__ __launch_bounds__(256) void vq_scores(const float* __restrict__ x,
                                                 const float* __restrict__ eT,
                                                 const float* __restrict__ esq,
                                                 float* __restrict__ cval,
                                                 int* __restrict__ cidx) {
    constexpr int XS = 132;   // padded d-major x tile stride (writes 2-way max)
    constexpr int ES = 128;   // e tile stride (staged pre-transposed: clean)
    constexpr int DK = 32;
    __shared__ __align__(16) float smem[DK * XS + DK * ES];  // 33280 B
    float* xs = smem;
    float* es = smem + DK * XS;

    const int tid = threadIdx.x;
    const int tc = tid & 15, tr = tid >> 4;
    const int rb = blockIdx.x >> 2, cs = blockIdx.x & 3;
    const int r0 = rb * 128;

    float minv[8];
    int   mini[8];
#pragma unroll
    for (int i = 0; i < 8; ++i) { minv[i] = FLT_MAX; mini[i] = 0; }

    for (int ct = 0; ct < 2; ++ct) {
        const int c0 = cs * 256 + ct * 128;
        float acc[64];
#pragma unroll
        for (int k = 0; k < 64; ++k) acc[k] = 0.f;

        for (int dk = 0; dk < 8; ++dk) {
            const int d0 = dk * DK;
            __syncthreads();
            // stage x chunk (transpose-write into d-major)
#pragma unroll
            for (int it = 0; it < 4; ++it) {
                int idx = it * 256 + tid;          // 1024 float4
                int row = idx >> 3, dq = idx & 7;
                float4 v = *(const float4*)&x[(r0 + row) * DIM + d0 + dq * 4];
                xs[(dq * 4 + 0) * XS + row] = v.x;
                xs[(dq * 4 + 1) * XS + row] = v.y;
                xs[(dq * 4 + 2) * XS + row] = v.z;
                xs[(dq * 4 + 3) * XS + row] = v.w;
            }
            // stage e chunk (already d-major in global)
#pragma unroll
            for (int it = 0; it < 4; ++it) {
                int idx = it * 256 + tid;
                int dd = idx >> 5, cq = idx & 31;
                *(float4*)&es[dd * ES + cq * 4] =
                    *(const float4*)&eT[(d0 + dd) * MCODE + c0 + cq * 4];
            }
            __syncthreads();

            const float* xp = xs + tr * 4;
            const float* ep = es + tc * 4;
#pragma unroll 8
            for (int d = 0; d < DK; ++d) {
                float4 xA = *(const float4*)&xp[d * XS];
                float4 xB = *(const float4*)&xp[d * XS + 64];
                float4 eA = *(const float4*)&ep[d * ES];
                float4 eB = *(const float4*)&ep[d * ES + 64];
                float xa[8] = {xA.x, xA.y, xA.z, xA.w, xB.x, xB.y, xB.z, xB.w};
                float ea[8] = {eA.x, eA.y, eA.z, eA.w, eB.x, eB.y, eB.z, eB.w};
#pragma unroll
                for (int i = 0; i < 8; ++i)
#pragma unroll
                    for (int j = 0; j < 8; ++j)
                        acc[i * 8 + j] = fmaf(xa[i], ea[j], acc[i * 8 + j]);
            }
        }
        // fold tile into running argmin (cols ascending -> numpy tie-break)
#pragma unroll
        for (int j = 0; j < 8; ++j) {
            int c = c0 + ((j < 4) ? (tc * 4 + j) : (64 + tc * 4 + (j - 4)));
            float ec = esq[c];
#pragma unroll
            for (int i = 0; i < 8; ++i) {
                float dist = fmaf(-2.f, acc[i * 8 + j], ec);
                if (dist < minv[i]) { minv[i] = dist; mini[i] = c; }
            }
        }
    }

    // cross-thread (tc) reduction per row; reuse smem
    __syncthreads();
    float* rmin = smem;                 // [16][128]
    int*   rarg = (int*)(smem + 2048);  // [16][128]
#pragma unroll
    for (int i = 0; i < 8; ++i) {
        int rl = (i < 4) ? (tr * 4 + i) : (64 + tr * 4 + (i - 4));
        rmin[tc * 128 + rl] = minv[i];
        rarg[tc * 128 + rl] = mini[i];
    }
    __syncthreads();
    if (tid < 128) {
        float bv = rmin[tid];
        int   bi = rarg[tid];
#pragma unroll
        for (int t = 1; t < 16; ++t) {
            float v = rmin[t * 128 + tid];
            int  ix = rarg[t * 128 + tid];
            if (v < bv || (v == bv && ix < bi)) { bv = v; bi = ix; }
        }
        cval[cs * N_TOK + r0 + tid] = bv;
        cidx[cs * N_TOK + r0 + tid] = bi;
    }
}

// merge candidates + quantize + straight-through + loss partial + scatter dw/counts
// 4096 blocks x 8 rows each
__global__ __launch_bounds__(256) void vq_assign(const float* __restrict__ x,
                                                 const float* __restrict__ emb,
                                                 const float* __restrict__ cval,
                                                 const int* __restrict__ cidx,
                                                 float* __restrict__ outq,
                                                 float* __restrict__ dw,
                                                 float* __restrict__ counts,
                                                 float* __restrict__ lpart) {
    const int tid = threadIdx.x;
    float lacc = 0.f;
    for (int r = 0; r < 8; ++r) {
        int row = blockIdx.x * 8 + r;
        float bv = cval[row];
        int   bi = cidx[row];
#pragma unroll
        for (int s = 1; s < 4; ++s) {
            float v = cval[s * N_TOK + row];
            int  ix = cidx[s * N_TOK + row];
            if (v < bv || (v == bv && ix < bi)) { bv = v; bi = ix; }
        }
        float xv = x[row * DIM + tid];
        float q  = emb[bi * DIM + tid];
        outq[row * DIM + tid] = xv + (q - xv);   // exact ref op order
        float diff = xv - q;
        lacc += diff * diff;
        atomicAdd(&dw[bi * DIM + tid], xv);
        if (tid == 0) atomicAdd(&counts[bi], 1.0f);
    }
#pragma unroll
    for (int off = 32; off; off >>= 1) lacc += __shfl_xor(lacc, off, 64);
    __shared__ float red[4];
    if ((tid & 63) == 0) red[tid >> 6] = lacc;
    __syncthreads();
    if (tid == 0) lpart[blockIdx.x] = red[0] + red[1] + red[2] + red[3];
}

// single block: new_count, perplexity, losses
__global__ __launch_bounds__(1024) void vq_finalize(const float* __restrict__ counts,
                                                    const float* __restrict__ ema_count,
                                                    const float* __restrict__ lpart,
                                                    float* __restrict__ out) {
    const int m = threadIdx.x;
    __shared__ float red[1024];
    float c   = counts[m];
    float raw = DECAY_ * ema_count[m] + OMD_ * c;
    red[m] = raw;
    __syncthreads();
    for (int s = 512; s; s >>= 1) { if (m < s) red[m] += red[m + s]; __syncthreads(); }
    float n = red[0];
    __syncthreads();
    out[OUT_NC + m] = (raw + EPS_) / (n + MEPS_) * n;

    float p = c / (float)N_TOK;
    red[m] = p * logf(p + 1e-10f);
    __syncthreads();
    for (int s = 512; s; s >>= 1) { if (m < s) red[m] += red[m + s]; __syncthreads(); }
    float ent = red[0];
    __syncthreads();

    float ls = 0.f;
#pragma unroll
    for (int k = 0; k < 4; ++k) ls += lpart[m + 1024 * k];
    red[m] = ls;
    __syncthreads();
    for (int s = 512; s; s >>= 1) { if (m < s) red[m] += red[m + s]; __syncthreads(); }
    if (m == 0) {
        float mean = red[0] / (float)(N_TOK * DIM);
        out[OUT_COMMIT]   = 0.25f * mean;
        out[OUT_CODEBOOK] = mean;
        out[OUT_PERP]     = expf(-ent);
    }
}

// new_weight + new_embedding; one block per code
__global__ __launch_bounds__(256) void vq_weight(const float* __restrict__ ema_weight,
                                                 const float* __restrict__ dw,
                                                 const float* __restrict__ ncnt,
                                                 float* __restrict__ out) {
    int m = blockIdx.x, d = threadIdx.x;
    float nw = DECAY_ * ema_weight[m * DIM + d] + OMD_ * dw[m * DIM + d];
    float nc = ncnt[m];
    out[OUT_NW + m * DIM + d] = nw;
    out[OUT_NE + m * DIM + d] = nw / nc;
}

extern "C" void kernel_launch(void* const* d_in, const int* in_sizes, int n_in,
                              void* d_out, int out_size, void* d_ws, size_t ws_size,
                              hipStream_t stream) {
    const float* x          = (const float*)d_in[0];
    const float* emb        = (const float*)d_in[1];
    const float* ema_count  = (const float*)d_in[2];
    const float* ema_weight = (const float*)d_in[3];
    float* out = (float*)d_out;
    float* wf  = (float*)d_ws;

    float* eT     = wf + WS_ET;
    float* esq    = wf + WS_ESQ;
    float* counts = wf + WS_CNT;
    float* dw     = wf + WS_DW;
    float* lpart  = wf + WS_LP;
    float* cval   = wf + WS_CVAL;
    int*   cidx   = (int*)(wf + WS_CIDX);

    const int nzero = WS_LP - WS_CNT;  // counts + dw
    vq_zero<<<(nzero + 255) / 256, 256, 0, stream>>>(counts, nzero);
    vq_esq<<<MCODE, 64, 0, stream>>>(emb, esq);
    vq_transpose<<<64, 256, 0, stream>>>(emb, eT);
    vq_scores<<<1024, 256, 0, stream>>>(x, eT, esq, cval, cidx);
    vq_assign<<<4096, 256, 0, stream>>>(x, emb, cval, cidx, out, dw, counts, lpart);
    vq_finalize<<<1, 1024, 0, stream>>>(counts, ema_count, lpart, out);
    vq_weight<<<MCODE, 256, 0, stream>>>(ema_weight, dw, out + OUT_NC, out);
}

// Round 3
// 205.637 us; speedup vs baseline: 1.7224x; 1.7224x over previous
//
#include <hip/hip_runtime.h>
#include <cfloat>
#include <math.h>

#define N_TOK 32768
#define DIM   256
#define MCODE 1024

typedef unsigned short u16;
typedef unsigned long long u64;
typedef __attribute__((ext_vector_type(8))) short short8;
typedef __attribute__((ext_vector_type(4))) float f32x4;

constexpr float DECAY_ = 0.999f;
constexpr float OMD_   = (float)(1.0 - 0.999);   // match jax double->f32 promotion
constexpr float EPS_   = 1e-5f;
constexpr float MEPS_  = (float)(1024 * 1e-5);   // M * EPS in double, then f32

// ---- workspace layout (float offsets) ----
// TOTAL = 595968 floats = 2,383,872 bytes. MUST stay <= 3,284,992 B (the
// Round-1-proven ws_size lower bound) — exceeding ws_size corrupts adjacent
// allocations (incl. harness pristine input copies) and fails post-timing.
constexpr int WS_EH   = 0;        // eh[1024*256] bf16 -> 131072 float slots
constexpr int WS_EL   = 131072;   // el           -> 131072
constexpr int WS_ESQ  = 262144;   // esq[1024]
constexpr int WS_CNT  = 263168;   // counts[1024]        (zeroed)
constexpr int WS_DW   = 264192;   // dw[1024][256]       (zeroed)
constexpr int WS_LP   = 526336;   // loss partials[4096]
constexpr int WS_KEY  = 530432;   // u64 keys[32768] (init ~0) -> 65536 float slots

// ---- output layout (float offsets) ----
constexpr int OUT_Q        = 0;
constexpr int OUT_COMMIT   = 8388608;
constexpr int OUT_CODEBOOK = 8388609;
constexpr int OUT_PERP     = 8388610;
constexpr int OUT_NE       = 8388611;
constexpr int OUT_NC       = 8650755;
constexpr int OUT_NW       = 8651779;

static __device__ __forceinline__ u16 f2bf(float f) {
    unsigned u = __float_as_uint(f);
    unsigned r = (u + 0x7fff + ((u >> 16) & 1)) >> 16;   // rn-even; NaN irrelevant here
    return (u16)r;
}
static __device__ __forceinline__ float bf2f(u16 h) {
    return __uint_as_float(((unsigned)h) << 16);
}
static __device__ __forceinline__ void gl2lds16(const u16* g, char* l) {
    __builtin_amdgcn_global_load_lds(
        (const __attribute__((address_space(1))) unsigned int*)g,
        (__attribute__((address_space(3))) unsigned int*)l, 16, 0, 0);
}
// monotone float->uint map: a<b  <=>  map(a)<map(b)  (finite floats)
static __device__ __forceinline__ unsigned fmap(float f) {
    unsigned u = __float_as_uint(f);
    return (u & 0x80000000u) ? ~u : (u | 0x80000000u);
}

__global__ __launch_bounds__(256) void vq_zero(float* __restrict__ p, int n) {
    int i = blockIdx.x * 256 + threadIdx.x;
    if (i < n) p[i] = 0.f;
}

__global__ __launch_bounds__(256) void vq_init_keys(u64* __restrict__ k, int n) {
    int i = blockIdx.x * 256 + threadIdx.x;
    if (i < n) k[i] = ~0ULL;
}

// one block (64 threads) per code: esq[c] = sum_d e[c][d]^2  (fp32, matches ref)
__global__ __launch_bounds__(64) void vq_esq(const float* __restrict__ emb,
                                             float* __restrict__ esq) {
    int c = blockIdx.x, l = threadIdx.x;
    float4 v = *(const float4*)&emb[c * DIM + l * 4];
    float s = v.x * v.x + v.y * v.y + v.z * v.z + v.w * v.w;
#pragma unroll
    for (int off = 32; off; off >>= 1) s += __shfl_xor(s, off, 64);
    if (l == 0) esq[c] = s;
}

// split fp32 -> (bf16 hi, bf16 residual) in MFMA-fragment global order:
// dst[((rb*8+kc)*8+t)*512 + lane*8 + j]  <->  src[row=rb*128+t*16+(lane&15)][k=kc*32+(lane>>4)*8+j]
__global__ __launch_bounds__(256) void vq_pack(const float* __restrict__ src,
                                               u16* __restrict__ dh,
                                               u16* __restrict__ dl,
                                               int n_wave) {
    int gtid = blockIdx.x * 256 + threadIdx.x;
    int wave_id = gtid >> 6, lane = gtid & 63;
    if (wave_id >= n_wave) return;
    int rb = wave_id >> 6, kc = (wave_id >> 3) & 7, t = wave_id & 7;
    int row = rb * 128 + t * 16 + (lane & 15);
    int k   = kc * 32 + (lane >> 4) * 8;
    const float* s = &src[row * DIM + k];
    float4 v0 = *(const float4*)s, v1 = *(const float4*)(s + 4);
    float vv[8] = {v0.x, v0.y, v0.z, v0.w, v1.x, v1.y, v1.z, v1.w};
    short8 hv, lv;
#pragma unroll
    for (int j = 0; j < 8; ++j) {
        float v = vv[j];
        u16 h = f2bf(v);
        float r = v - bf2f(h);
        hv[j] = (short)h;
        lv[j] = (short)f2bf(r);
    }
    size_t o = (size_t)wave_id * 512 + lane * 8;
    *(short8*)&dh[o] = hv;
    *(short8*)&dl[o] = lv;
}

// main MFMA scores+argmin: grid 2048 = 256 row-blocks x 8 col-splits.
// block = 128 rows x 128 cols, 4 waves in 2x2, wave = 64x64 = 4x4 grid of 16x16x32.
// dot = xh*eh + xh*el + xl*eh (3 MFMA); dist = esq[c] - 2*dot.
// per-row winner merged across col-splits via atomicMin on packed (dist,idx) key.
__global__ __launch_bounds__(256) void vq_scores_mfma(const u16* __restrict__ xh,
                                                      const u16* __restrict__ xl,
                                                      const u16* __restrict__ eh,
                                                      const u16* __restrict__ el,
                                                      const float* __restrict__ esq,
                                                      u64* __restrict__ keys) {
    __shared__ __align__(16) char smem[33792];
    const int tid  = threadIdx.x;
    const int lane = tid & 63, w = tid >> 6;
    const int wm = w & 1, wn = w >> 1;
    const int rb = blockIdx.x >> 3, cs = blockIdx.x & 7;

    const u16* gb[4] = {xh + (size_t)rb * 32768, xl + (size_t)rb * 32768,
                        eh + (size_t)cs * 32768, el + (size_t)cs * 32768};

    const short8* Ah = (const short8*)(smem);
    const short8* Al = (const short8*)(smem + 8192);
    const short8* Bh = (const short8*)(smem + 16384);
    const short8* Bl = (const short8*)(smem + 24576);

    f32x4 acc[4][4];
#pragma unroll
    for (int i = 0; i < 4; ++i)
#pragma unroll
        for (int j = 0; j < 4; ++j) acc[i][j] = (f32x4)0.f;

    for (int kc = 0; kc < 8; ++kc) {
        __syncthreads();   // previous chunk's frag reads done before overwrite
        {
            const u16* g = gb[w] + kc * 4096 + lane * 8;
            char* l = smem + w * 8192;
#pragma unroll
            for (int s2 = 0; s2 < 8; ++s2)
                gl2lds16(g + s2 * 512, l + s2 * 1024);
        }
        __syncthreads();   // drains vmcnt (incl. global_load_lds) + barrier

        short8 ah[4], al[4];
#pragma unroll
        for (int tm = 0; tm < 4; ++tm) {
            int idx = (wm * 4 + tm) * 64 + lane;
            ah[tm] = Ah[idx];
            al[tm] = Al[idx];
        }
#pragma unroll
        for (int tn = 0; tn < 4; ++tn) {
            int bidx = (wn * 4 + tn) * 64 + lane;
            short8 bh = Bh[bidx], bl = Bl[bidx];
#pragma unroll
            for (int tm = 0; tm < 4; ++tm) {
                acc[tm][tn] = __builtin_amdgcn_mfma_f32_16x16x32_bf16(ah[tm], bh, acc[tm][tn], 0, 0, 0);
                acc[tm][tn] = __builtin_amdgcn_mfma_f32_16x16x32_bf16(al[tm], bh, acc[tm][tn], 0, 0, 0);
                acc[tm][tn] = __builtin_amdgcn_mfma_f32_16x16x32_bf16(ah[tm], bl, acc[tm][tn], 0, 0, 0);
            }
        }
    }

    // epilogue: dist = esq - 2*acc, per-row argmin.
    // C/D layout: col = lane&15, row = (lane>>4)*4 + reg (m89/m91-verified)
    __syncthreads();
    float* cv = (float*)smem;            // [128 rows][33 slots] (pad 33: conflict-free)
    int*   ci = (int*)(smem + 16896);
    const int ln = lane & 15, quad = lane >> 4;
#pragma unroll
    for (int tm = 0; tm < 4; ++tm) {
        float bv[4];
        int   bi[4];
#pragma unroll
        for (int r = 0; r < 4; ++r) { bv[r] = FLT_MAX; bi[r] = 0; }
#pragma unroll
        for (int tn = 0; tn < 4; ++tn) {          // ascending col -> strict < keeps lowest idx
            int c = cs * 128 + wn * 64 + tn * 16 + ln;
            float ec = esq[c];
#pragma unroll
            for (int r = 0; r < 4; ++r) {
                float d = fmaf(-2.f, acc[tm][tn][r], ec);
                if (d < bv[r]) { bv[r] = d; bi[r] = c; }
            }
        }
        int row0 = wm * 64 + tm * 16 + quad * 4;
        int slot = wn * 16 + ln;
#pragma unroll
        for (int r = 0; r < 4; ++r) {
            cv[(row0 + r) * 33 + slot] = bv[r];
            ci[(row0 + r) * 33 + slot] = bi[r];
        }
    }
    __syncthreads();
    if (tid < 128) {
        float bv = cv[tid * 33];
        int   bi = ci[tid * 33];
#pragma unroll
        for (int s = 1; s < 32; ++s) {
            float v = cv[tid * 33 + s];
            int  ix = ci[tid * 33 + s];
            if (v < bv || (v == bv && ix < bi)) { bv = v; bi = ix; }
        }
        u64 key = ((u64)fmap(bv) << 32) | (unsigned)bi;
        atomicMin(&keys[rb * 128 + tid], key);
    }
}

// quantize + straight-through + loss partial + scatter dw/counts
__global__ __launch_bounds__(256) void vq_assign(const float* __restrict__ x,
                                                 const float* __restrict__ emb,
                                                 const u64* __restrict__ keys,
                                                 float* __restrict__ outq,
                                                 float* __restrict__ dw,
                                                 float* __restrict__ counts,
                                                 float* __restrict__ lpart) {
    const int tid = threadIdx.x;
    float lacc = 0.f;
    for (int r = 0; r < 8; ++r) {
        int row = blockIdx.x * 8 + r;
        int bi = (int)(unsigned)(keys[row] & 0xffffffffULL);
        float xv = x[row * DIM + tid];
        float q  = emb[bi * DIM + tid];
        outq[row * DIM + tid] = xv + (q - xv);   // exact ref op order
        float diff = xv - q;
        lacc += diff * diff;
        atomicAdd(&dw[bi * DIM + tid], xv);
        if (tid == 0) atomicAdd(&counts[bi], 1.0f);
    }
#pragma unroll
    for (int off = 32; off; off >>= 1) lacc += __shfl_xor(lacc, off, 64);
    __shared__ float red[4];
    if ((tid & 63) == 0) red[tid >> 6] = lacc;
    __syncthreads();
    if (tid == 0) lpart[blockIdx.x] = red[0] + red[1] + red[2] + red[3];
}

// single block: new_count, perplexity, losses
__global__ __launch_bounds__(1024) void vq_finalize(const float* __restrict__ counts,
                                                    const float* __restrict__ ema_count,
                                                    const float* __restrict__ lpart,
                                                    float* __restrict__ out) {
    const int m = threadIdx.x;
    __shared__ float red[1024];
    float c   = counts[m];
    float raw = DECAY_ * ema_count[m] + OMD_ * c;
    red[m] = raw;
    __syncthreads();
    for (int s = 512; s; s >>= 1) { if (m < s) red[m] += red[m + s]; __syncthreads(); }
    float n = red[0];
    __syncthreads();
    out[OUT_NC + m] = (raw + EPS_) / (n + MEPS_) * n;

    float p = c / (float)N_TOK;
    red[m] = p * logf(p + 1e-10f);
    __syncthreads();
    for (int s = 512; s; s >>= 1) { if (m < s) red[m] += red[m + s]; __syncthreads(); }
    float ent = red[0];
    __syncthreads();

    float ls = 0.f;
#pragma unroll
    for (int k = 0; k < 4; ++k) ls += lpart[m + 1024 * k];
    red[m] = ls;
    __syncthreads();
    for (int s = 512; s; s >>= 1) { if (m < s) red[m] += red[m + s]; __syncthreads(); }
    if (m == 0) {
        float mean = red[0] / (float)(N_TOK * DIM);
        out[OUT_COMMIT]   = 0.25f * mean;
        out[OUT_CODEBOOK] = mean;
        out[OUT_PERP]     = expf(-ent);
    }
}

// new_weight + new_embedding; one block per code
__global__ __launch_bounds__(256) void vq_weight(const float* __restrict__ ema_weight,
                                                 const float* __restrict__ dw,
                                                 const float* __restrict__ ncnt,
                                                 float* __restrict__ out) {
    int m = blockIdx.x, d = threadIdx.x;
    float nw = DECAY_ * ema_weight[m * DIM + d] + OMD_ * dw[m * DIM + d];
    float nc = ncnt[m];
    out[OUT_NW + m * DIM + d] = nw;
    out[OUT_NE + m * DIM + d] = nw / nc;
}

extern "C" void kernel_launch(void* const* d_in, const int* in_sizes, int n_in,
                              void* d_out, int out_size, void* d_ws, size_t ws_size,
                              hipStream_t stream) {
    const float* x          = (const float*)d_in[0];
    const float* emb        = (const float*)d_in[1];
    const float* ema_count  = (const float*)d_in[2];
    const float* ema_weight = (const float*)d_in[3];
    float* out = (float*)d_out;
    float* wf  = (float*)d_ws;

    // xh/xl live in the d_out quantized region (exactly 33.5 MB); vq_assign
    // overwrites it afterwards.
    u16* xh = (u16*)d_out;
    u16* xl = xh + (size_t)N_TOK * DIM;
    u16* eh = (u16*)(wf + WS_EH);
    u16* el = (u16*)(wf + WS_EL);

    float* esq    = wf + WS_ESQ;
    float* counts = wf + WS_CNT;
    float* dw     = wf + WS_DW;
    float* lpart  = wf + WS_LP;
    u64*   keys   = (u64*)(wf + WS_KEY);

    const int nzero = WS_LP - WS_CNT;  // counts + dw
    vq_zero<<<(nzero + 255) / 256, 256, 0, stream>>>(counts, nzero);
    vq_init_keys<<<128, 256, 0, stream>>>(keys, N_TOK);
    vq_esq<<<MCODE, 64, 0, stream>>>(emb, esq);
    vq_pack<<<4096, 256, 0, stream>>>(x, xh, xl, 16384);    // x: 256 rb * 8 kc * 8 t
    vq_pack<<<128, 256, 0, stream>>>(emb, eh, el, 512);     // e: 8 cb * 8 kc * 8 t
    vq_scores_mfma<<<2048, 256, 0, stream>>>(xh, xl, eh, el, esq, keys);
    vq_assign<<<4096, 256, 0, stream>>>(x, emb, keys, out, dw, counts, lpart);
    vq_finalize<<<1, 1024, 0, stream>>>(counts, ema_count, lpart, out);
    vq_weight<<<MCODE, 256, 0, stream>>>(ema_weight, dw, out + OUT_NC, out);
}

// Round 4
// 186.294 us; speedup vs baseline: 1.9012x; 1.1038x over previous
//
#include <hip/hip_runtime.h>
#include <cfloat>
#include <math.h>

#define N_TOK 32768
#define DIM   256
#define MCODE 1024

typedef unsigned short u16;
typedef unsigned long long u64;
typedef __attribute__((ext_vector_type(8))) short short8;
typedef __attribute__((ext_vector_type(4))) float f32x4;

constexpr float DECAY_ = 0.999f;
constexpr float OMD_   = (float)(1.0 - 0.999);   // match jax double->f32 promotion
constexpr float EPS_   = 1e-5f;
constexpr float MEPS_  = (float)(1024 * 1e-5);   // M * EPS in double, then f32

// ---- workspace layout (float offsets) ----
// TOTAL = 399360 floats = 1,597,440 B. MUST stay <= 3,284,992 B (Round-1-proven
// ws_size bound) — overflow corrupts harness pristine copies (Round-2 failure).
constexpr int WS_EH     = 0;        // eh[1024*256] bf16 -> 131072 float slots
constexpr int WS_EL     = 131072;   // el           -> 131072
constexpr int WS_ESQ    = 262144;   // esq[1024]
constexpr int WS_CNTI   = 263168;   // int counts[1024] (zeroed in prep)
constexpr int WS_START  = 264192;   // int start[1024]
constexpr int WS_CURSOR = 265216;   // int cursor[1024]
constexpr int WS_BI     = 266240;   // int bi[32768]
constexpr int WS_ROWL   = 299008;   // int rowlist[32768]
constexpr int WS_LP     = 331776;   // loss partials[2048]
constexpr int WS_KEY    = 333824;   // u64 keys[32768] (8B-aligned: 333824*4%8==0)

// ---- output layout (float offsets) ----
constexpr int OUT_Q        = 0;
constexpr int OUT_COMMIT   = 8388608;
constexpr int OUT_CODEBOOK = 8388609;
constexpr int OUT_PERP     = 8388610;
constexpr int OUT_NE       = 8388611;
constexpr int OUT_NC       = 8650755;
constexpr int OUT_NW       = 8651779;

static __device__ __forceinline__ u16 f2bf(float f) {
    unsigned u = __float_as_uint(f);
    unsigned r = (u + 0x7fff + ((u >> 16) & 1)) >> 16;   // rn-even
    return (u16)r;
}
static __device__ __forceinline__ float bf2f(u16 h) {
    return __uint_as_float(((unsigned)h) << 16);
}
static __device__ __forceinline__ void gl2lds16(const u16* g, char* l) {
    __builtin_amdgcn_global_load_lds(
        (const __attribute__((address_space(1))) unsigned int*)g,
        (__attribute__((address_space(3))) unsigned int*)l, 16, 0, 0);
}
// monotone float->uint map: a<b  <=>  map(a)<map(b)  (finite floats)
static __device__ __forceinline__ unsigned fmap(float f) {
    unsigned u = __float_as_uint(f);
    return (u & 0x80000000u) ? ~u : (u | 0x80000000u);
}

// split fp32 -> (bf16 hi, bf16 residual) in MFMA-fragment global order:
// dst[wave*512 + lane*8 + j] <-> src[row=(wave>>6)*128+(wave&7)*16+(lane&15)]
//                                   [k=((wave>>3)&7)*32+(lane>>4)*8+j]
static __device__ __forceinline__ void pack_wave(const float* __restrict__ src,
                                                 u16* __restrict__ dh,
                                                 u16* __restrict__ dl,
                                                 int wave_id, int lane) {
    int rb = wave_id >> 6, kc = (wave_id >> 3) & 7, t = wave_id & 7;
    int row = rb * 128 + t * 16 + (lane & 15);
    int k   = kc * 32 + (lane >> 4) * 8;
    const float* s = &src[row * DIM + k];
    float4 v0 = *(const float4*)s, v1 = *(const float4*)(s + 4);
    float vv[8] = {v0.x, v0.y, v0.z, v0.w, v1.x, v1.y, v1.z, v1.w};
    short8 hv, lv;
#pragma unroll
    for (int j = 0; j < 8; ++j) {
        float v = vv[j];
        u16 h = f2bf(v);
        float r = v - bf2f(h);
        hv[j] = (short)h;
        lv[j] = (short)f2bf(r);
    }
    size_t o = (size_t)wave_id * 512 + lane * 8;
    *(short8*)&dh[o] = hv;
    *(short8*)&dl[o] = lv;
}

// fused setup: pack e (blocks 0..127), esq (128..383), keys init (384..511),
// int counts zero (512)
__global__ __launch_bounds__(256) void vq_prep(const float* __restrict__ emb,
                                               u16* __restrict__ eh,
                                               u16* __restrict__ el,
                                               float* __restrict__ esq,
                                               u64* __restrict__ keys,
                                               int* __restrict__ cnti) {
    const int b = blockIdx.x, tid = threadIdx.x;
    const int lane = tid & 63, w = tid >> 6;
    if (b < 128) {
        pack_wave(emb, eh, el, b * 4 + w, lane);
    } else if (b < 384) {
        int c = (b - 128) * 4 + w;
        float4 v = *(const float4*)&emb[c * DIM + lane * 4];
        float s = v.x * v.x + v.y * v.y + v.z * v.z + v.w * v.w;
#pragma unroll
        for (int off = 32; off; off >>= 1) s += __shfl_xor(s, off, 64);
        if (lane == 0) esq[c] = s;
    } else if (b < 512) {
        keys[(b - 384) * 256 + tid] = ~0ULL;
    } else {
#pragma unroll
        for (int i = 0; i < 4; ++i) cnti[i * 256 + tid] = 0;
    }
}

__global__ __launch_bounds__(256) void vq_pack_x(const float* __restrict__ x,
                                                 u16* __restrict__ xh,
                                                 u16* __restrict__ xl) {
    int gtid = blockIdx.x * 256 + threadIdx.x;
    pack_wave(x, xh, xl, gtid >> 6, gtid & 63);
}

// main MFMA scores+argmin: 2048 blocks; swizzled so all 8 col-splits of a
// row-block land on the SAME XCD (idx%8 == rb%8) and are <=56 dispatches
// apart -> x tiles served from per-XCD L2 instead of 8x HBM refetch.
// block = 128 rows x 128 cols, 4 waves 2x2, wave = 4x4 grid of 16x16x32.
// dot = xh*eh + xh*el + xl*eh (3 MFMA); dist = esq[c] - 2*dot.
__global__ __launch_bounds__(256) void vq_scores_mfma(const u16* __restrict__ xh,
                                                      const u16* __restrict__ xl,
                                                      const u16* __restrict__ eh,
                                                      const u16* __restrict__ el,
                                                      const float* __restrict__ esq,
                                                      u64* __restrict__ keys) {
    __shared__ __align__(16) char smem[33792];
    const int tid  = threadIdx.x;
    const int lane = tid & 63, w = tid >> 6;
    const int wm = w & 1, wn = w >> 1;
    const int raw = blockIdx.x;
    const int rb = (raw >> 6) * 8 + (raw & 7);
    const int cs = (raw >> 3) & 7;

    const u16* gb[4] = {xh + (size_t)rb * 32768, xl + (size_t)rb * 32768,
                        eh + (size_t)cs * 32768, el + (size_t)cs * 32768};

    const short8* Ah = (const short8*)(smem);
    const short8* Al = (const short8*)(smem + 8192);
    const short8* Bh = (const short8*)(smem + 16384);
    const short8* Bl = (const short8*)(smem + 24576);

    f32x4 acc[4][4];
#pragma unroll
    for (int i = 0; i < 4; ++i)
#pragma unroll
        for (int j = 0; j < 4; ++j) acc[i][j] = (f32x4)0.f;

    for (int kc = 0; kc < 8; ++kc) {
        __syncthreads();   // previous chunk's frag reads done before overwrite
        {
            const u16* g = gb[w] + kc * 4096 + lane * 8;
            char* l = smem + w * 8192;
#pragma unroll
            for (int s2 = 0; s2 < 8; ++s2)
                gl2lds16(g + s2 * 512, l + s2 * 1024);
        }
        __syncthreads();   // drains vmcnt (incl. global_load_lds) + barrier

        short8 ah[4], al[4];
#pragma unroll
        for (int tm = 0; tm < 4; ++tm) {
            int idx = (wm * 4 + tm) * 64 + lane;
            ah[tm] = Ah[idx];
            al[tm] = Al[idx];
        }
#pragma unroll
        for (int tn = 0; tn < 4; ++tn) {
            int bidx = (wn * 4 + tn) * 64 + lane;
            short8 bh = Bh[bidx], bl = Bl[bidx];
#pragma unroll
            for (int tm = 0; tm < 4; ++tm) {
                acc[tm][tn] = __builtin_amdgcn_mfma_f32_16x16x32_bf16(ah[tm], bh, acc[tm][tn], 0, 0, 0);
                acc[tm][tn] = __builtin_amdgcn_mfma_f32_16x16x32_bf16(al[tm], bh, acc[tm][tn], 0, 0, 0);
                acc[tm][tn] = __builtin_amdgcn_mfma_f32_16x16x32_bf16(ah[tm], bl, acc[tm][tn], 0, 0, 0);
            }
        }
    }

    // epilogue: dist = esq - 2*acc, per-row argmin.
    // C/D layout: col = lane&15, row = (lane>>4)*4 + reg (m89/m91-verified)
    __syncthreads();
    float* cv = (float*)smem;            // [128 rows][33 slots] pad -> conflict-free
    int*   ci = (int*)(smem + 16896);
    const int ln = lane & 15, quad = lane >> 4;
#pragma unroll
    for (int tm = 0; tm < 4; ++tm) {
        float bv[4];
        int   bi[4];
#pragma unroll
        for (int r = 0; r < 4; ++r) { bv[r] = FLT_MAX; bi[r] = 0; }
#pragma unroll
        for (int tn = 0; tn < 4; ++tn) {          // ascending col -> lowest-idx ties
            int c = cs * 128 + wn * 64 + tn * 16 + ln;
            float ec = esq[c];
#pragma unroll
            for (int r = 0; r < 4; ++r) {
                float d = fmaf(-2.f, acc[tm][tn][r], ec);
                if (d < bv[r]) { bv[r] = d; bi[r] = c; }
            }
        }
        int row0 = wm * 64 + tm * 16 + quad * 4;
        int slot = wn * 16 + ln;
#pragma unroll
        for (int r = 0; r < 4; ++r) {
            cv[(row0 + r) * 33 + slot] = bv[r];
            ci[(row0 + r) * 33 + slot] = bi[r];
        }
    }
    __syncthreads();
    if (tid < 128) {
        float bv = cv[tid * 33];
        int   bi = ci[tid * 33];
#pragma unroll
        for (int s = 1; s < 32; ++s) {
            float v = cv[tid * 33 + s];
            int  ix = ci[tid * 33 + s];
            if (v < bv || (v == bv && ix < bi)) { bv = v; bi = ix; }
        }
        u64 key = ((u64)fmap(bv) << 32) | (unsigned)bi;
        atomicMin(&keys[rb * 128 + tid], key);
    }
}

// streaming quantize + straight-through + loss partials + histogram + bi array.
// 2048 blocks x 16 rows; float4 throughout; one int atomic per row.
__global__ __launch_bounds__(256) void vq_quant(const float* __restrict__ x,
                                                const float* __restrict__ emb,
                                                const u64* __restrict__ keys,
                                                float* __restrict__ outq,
                                                int* __restrict__ cnti,
                                                int* __restrict__ bi_arr,
                                                float* __restrict__ lpart) {
    const int tid = threadIdx.x, lane = tid & 63, w = tid >> 6;
    const float4* x4 = (const float4*)x;
    const float4* e4 = (const float4*)emb;
    float4* o4 = (float4*)outq;
    float lacc = 0.f;
#pragma unroll
    for (int it = 0; it < 4; ++it) {
        int row = blockIdx.x * 16 + it * 4 + w;
        int bi = (int)(unsigned)(keys[row] & 0xffffffffULL);
        if (lane == 0) { atomicAdd(&cnti[bi], 1); bi_arr[row] = bi; }
        float4 xv = x4[row * 64 + lane];
        float4 ev = e4[bi * 64 + lane];
        float4 q;
        q.x = xv.x + (ev.x - xv.x);  q.y = xv.y + (ev.y - xv.y);
        q.z = xv.z + (ev.z - xv.z);  q.w = xv.w + (ev.w - xv.w);
        o4[row * 64 + lane] = q;
        float dx = xv.x - ev.x, dy = xv.y - ev.y, dz = xv.z - ev.z, dwv = xv.w - ev.w;
        lacc += dx * dx + dy * dy + dz * dz + dwv * dwv;
    }
#pragma unroll
    for (int off = 32; off; off >>= 1) lacc += __shfl_xor(lacc, off, 64);
    __shared__ float red[4];
    if (lane == 0) red[w] = lacc;
    __syncthreads();
    if (tid == 0) lpart[blockIdx.x] = red[0] + red[1] + red[2] + red[3];
}

// single block: exclusive prefix sum of counts -> start, cursor
__global__ __launch_bounds__(1024) void vq_scan(const int* __restrict__ cnti,
                                                int* __restrict__ start,
                                                int* __restrict__ cursor) {
    const int m = threadIdx.x;
    __shared__ int s[1024];
    int v = cnti[m];
    s[m] = v;
    __syncthreads();
    for (int off = 1; off < 1024; off <<= 1) {
        int t = (m >= off) ? s[m - off] : 0;
        __syncthreads();
        s[m] += t;
        __syncthreads();
    }
    int excl = s[m] - v;
    start[m] = excl;
    cursor[m] = excl;
}

// bucket rows by code
__global__ __launch_bounds__(256) void vq_fill(const int* __restrict__ bi_arr,
                                               int* __restrict__ cursor,
                                               int* __restrict__ rowlist) {
    int row = blockIdx.x * 256 + threadIdx.x;
    int bi = bi_arr[row];
    int slot = atomicAdd(&cursor[bi], 1);
    rowlist[slot] = row;
}

// single block: new_count, perplexity, losses
__global__ __launch_bounds__(1024) void vq_finalize(const int* __restrict__ cnti,
                                                    const float* __restrict__ ema_count,
                                                    const float* __restrict__ lpart,
                                                    float* __restrict__ out) {
    const int m = threadIdx.x;
    __shared__ float red[1024];
    float c   = (float)cnti[m];
    float raw = DECAY_ * ema_count[m] + OMD_ * c;
    red[m] = raw;
    __syncthreads();
    for (int s = 512; s; s >>= 1) { if (m < s) red[m] += red[m + s]; __syncthreads(); }
    float n = red[0];
    __syncthreads();
    out[OUT_NC + m] = (raw + EPS_) / (n + MEPS_) * n;

    float p = c / (float)N_TOK;
    red[m] = p * logf(p + 1e-10f);
    __syncthreads();
    for (int s = 512; s; s >>= 1) { if (m < s) red[m] += red[m + s]; __syncthreads(); }
    float ent = red[0];
    __syncthreads();

    red[m] = lpart[m] + lpart[m + 1024];
    __syncthreads();
    for (int s = 512; s; s >>= 1) { if (m < s) red[m] += red[m + s]; __syncthreads(); }
    if (m == 0) {
        float mean = red[0] / (float)(N_TOK * DIM);
        out[OUT_COMMIT]   = 0.25f * mean;
        out[OUT_CODEBOOK] = mean;
        out[OUT_PERP]     = expf(-ent);
    }
}

// per-code sum of assigned x rows (replaces dw atomics) + EMA weight + embedding
__global__ __launch_bounds__(256) void vq_wsum(const float* __restrict__ x,
                                               const int* __restrict__ rowlist,
                                               const int* __restrict__ start,
                                               const int* __restrict__ cnti,
                                               const float* __restrict__ ema_weight,
                                               float* __restrict__ out) {
    const int m = blockIdx.x, d = threadIdx.x;
    int s0 = start[m], n = cnti[m], e = s0 + n;
    float a0 = 0.f, a1 = 0.f, a2 = 0.f, a3 = 0.f;
    int i = s0;
    for (; i + 4 <= e; i += 4) {                 // 4-way ILP over random rows
        int r0 = rowlist[i], r1 = rowlist[i + 1];
        int r2 = rowlist[i + 2], r3 = rowlist[i + 3];
        a0 += x[r0 * DIM + d];
        a1 += x[r1 * DIM + d];
        a2 += x[r2 * DIM + d];
        a3 += x[r3 * DIM + d];
    }
    for (; i < e; ++i) a0 += x[rowlist[i] * DIM + d];
    float dwsum = (a0 + a1) + (a2 + a3);
    float nw = DECAY_ * ema_weight[m * DIM + d] + OMD_ * dwsum;
    float nc = out[OUT_NC + m];
    out[OUT_NW + m * DIM + d] = nw;
    out[OUT_NE + m * DIM + d] = nw / nc;
}

extern "C" void kernel_launch(void* const* d_in, const int* in_sizes, int n_in,
                              void* d_out, int out_size, void* d_ws, size_t ws_size,
                              hipStream_t stream) {
    const float* x          = (const float*)d_in[0];
    const float* emb        = (const float*)d_in[1];
    const float* ema_count  = (const float*)d_in[2];
    const float* ema_weight = (const float*)d_in[3];
    float* out = (float*)d_out;
    float* wf  = (float*)d_ws;

    // xh/xl live in the d_out quantized region (33.5 MB); vq_quant overwrites
    // it afterwards.
    u16* xh = (u16*)d_out;
    u16* xl = xh + (size_t)N_TOK * DIM;
    u16* eh = (u16*)(wf + WS_EH);
    u16* el = (u16*)(wf + WS_EL);

    float* esq    = wf + WS_ESQ;
    int*   cnti   = (int*)(wf + WS_CNTI);
    int*   start  = (int*)(wf + WS_START);
    int*   cursor = (int*)(wf + WS_CURSOR);
    int*   bi_arr = (int*)(wf + WS_BI);
    int*   rowl   = (int*)(wf + WS_ROWL);
    float* lpart  = wf + WS_LP;
    u64*   keys   = (u64*)(wf + WS_KEY);

    vq_prep<<<513, 256, 0, stream>>>(emb, eh, el, esq, keys, cnti);
    vq_pack_x<<<4096, 256, 0, stream>>>(x, xh, xl);
    vq_scores_mfma<<<2048, 256, 0, stream>>>(xh, xl, eh, el, esq, keys);
    vq_quant<<<2048, 256, 0, stream>>>(x, emb, keys, out, cnti, bi_arr, lpart);
    vq_scan<<<1, 1024, 0, stream>>>(cnti, start, cursor);
    vq_fill<<<128, 256, 0, stream>>>(bi_arr, cursor, rowl);
    vq_finalize<<<1, 1024, 0, stream>>>(cnti, ema_count, lpart, out);
    vq_wsum<<<MCODE, 256, 0, stream>>>(x, rowl, start, cnti, ema_weight, out);
}